// Round 1
// baseline (121.671 us; speedup 1.0000x reference)
//
#include <hip/hip_runtime.h>

// MLP3D fused, MI355X gfx950 — round 8: occupancy doubling.
// r7 was 2 blocks/CU (LDS 68KB, ~256 total regs: 128 arch + 128 AGPR acc) ->
// MfmaUtil 32% + VALUBusy 39% with ~30% barrier stall. This round: M_PB=64,
// acc[4][4] (64 regs), 2-buffer A-prefetch (32 regs), LDS 34.8KB ->
// target 4 blocks/CU (16 waves) under __launch_bounds__(256,4).
// Prefetch discipline unchanged from r7 fix: A[j&1] reloaded only AFTER the
// MFMA that consumes it (lookahead 2).

#define NPTS 131072
#define M_PB 64
#define AST 264   // activation row stride in halves (256+8)

typedef _Float16 half8   __attribute__((ext_vector_type(8)));
typedef _Float16 half4_t __attribute__((ext_vector_type(4)));
typedef __fp16   fp16x2  __attribute__((ext_vector_type(2)));
typedef float    float4_t __attribute__((ext_vector_type(4)));

// ---- prep: W (f32 [K][256]) -> f16 per-wave-contiguous fragment layout ----
// dst[(((s*KB + kb)*4 + tn)*64 + l)*8 + j] = W[(kb*32 + (l>>4)*8 + j)*256 + s*64 + tn*16 + (l&15)]
__global__ void prep(const float* __restrict__ W0, const float* __restrict__ W1,
                     const float* __restrict__ W2, _Float16* __restrict__ ws) {
  int id = blockIdx.x * 256 + threadIdx.x;   // 147456 total
  _Float16 v;
  if (id < 16384) {            // W0sw: 4 slices x 2 kb x 4 tn x 512
    int e = id, j = e & 7, l = (e >> 3) & 63, tn = (e >> 9) & 3, kb = (e >> 11) & 1, s = e >> 12;
    int k = kb * 32 + (l >> 4) * 8 + j, n = s * 64 + tn * 16 + (l & 15);
    v = (k < 63) ? (_Float16)W0[k * 256 + n] : (_Float16)0.f;
  } else if (id < 81920) {     // W1sw: 4 x 8 x 4 x 512
    int e = id - 16384, j = e & 7, l = (e >> 3) & 63, tn = (e >> 9) & 3, kb = (e >> 11) & 7, s = e >> 14;
    int k = kb * 32 + (l >> 4) * 8 + j, n = s * 64 + tn * 16 + (l & 15);
    v = (_Float16)W1[k * 256 + n];
  } else {                     // W2sw
    int e = id - 81920, j = e & 7, l = (e >> 3) & 63, tn = (e >> 9) & 3, kb = (e >> 11) & 7, s = e >> 14;
    int k = kb * 32 + (l >> 4) * 8 + j, n = s * 64 + tn * 16 + (l & 15);
    v = (_Float16)W2[k * 256 + n];
  }
  ws[id] = v;
}

__device__ __forceinline__ half4_t pack4(float a, float b, float cc, float d) {
  fp16x2 p0 = __builtin_amdgcn_cvt_pkrtz(a, b);
  fp16x2 p1 = __builtin_amdgcn_cvt_pkrtz(cc, d);
  half4_t h;
  h[0] = (_Float16)p0[0]; h[1] = (_Float16)p0[1];
  h[2] = (_Float16)p1[0]; h[3] = (_Float16)p1[1];
  return h;
}

__global__ __launch_bounds__(256, 4) void mlp_main(
    const float* __restrict__ coords,
    const _Float16* __restrict__ W0sw,
    const _Float16* __restrict__ W1sw,
    const _Float16* __restrict__ W2sw,
    const float* __restrict__ b0, const float* __restrict__ b1,
    const float* __restrict__ b2,
    const float* __restrict__ Wocc, const float* __restrict__ bocc,
    const float* __restrict__ Wc, const float* __restrict__ bc,
    float* __restrict__ out) {
  __shared__ _Float16 actX[M_PB * AST];   // E -> h -> t1 (one buffer, barriered)
  __shared__ float occ_s[4][M_PB];

  const int t = threadIdx.x;
  const int w = t >> 6;          // wave = neuron slice [64w,64w+64) = part id
  const int l = t & 63;
  const int c = l & 15;
  const int q = l >> 4;
  const int m0 = blockIdx.x * M_PB;

  // ---- positional encoding: 4 threads/point, 16 k-values each ----
  {
    int m = t & 63, kh = (t >> 6) * 16;   // kh wave-uniform
    const float* cp = coords + (size_t)(m0 + m) * 3;
    float x0 = cp[0], x1 = cp[1], x2 = cp[2];
#pragma unroll
    for (int i = 0; i < 2; ++i) {
      float v[8];
#pragma unroll
      for (int u = 0; u < 8; ++u) {
        int k = kh + i * 8 + u;
        float r;
        if (k >= 63) r = 0.f;
        else if (k < 3) r = (k == 0) ? x0 : (k == 1 ? x1 : x2);
        else {
          int kk = k - 3;
          int f = kk / 6;
          int rem = kk - 6 * f;
          int s = (rem >= 3) ? 1 : 0;
          int i3 = rem - 3 * s;
          float xi = (i3 == 0) ? x0 : (i3 == 1 ? x1 : x2);
          float arg = xi * (float)(1 << f);
          float nn = rintf(arg * 0.15915494309189535f);
          float rr = fmaf(nn, -6.28318548202514648f, arg);
          rr = fmaf(nn, 1.7484555e-7f, rr);
          r = s ? __cosf(rr) : __sinf(rr);
        }
        v[u] = r;
      }
      half8 ev;
#pragma unroll
      for (int u = 0; u < 4; ++u) {
        fp16x2 p = __builtin_amdgcn_cvt_pkrtz(v[2 * u], v[2 * u + 1]);
        ev[2 * u] = (_Float16)p[0]; ev[2 * u + 1] = (_Float16)p[1];
      }
      *(half8*)&actX[m * AST + kh + i * 8] = ev;
    }
  }
  __syncthreads();                                   // (1) E ready

  float4_t acc[4][4];
  const _Float16* ap = actX + c * AST + q * 8;

  // ---- layer 0: h = E @ W0 + b0 (no relu), K=64 (2 kb, all A upfront) ----
  {
    const _Float16* wb = W0sw + (size_t)w * 4096 + l * 8;  // slice stride 2*4*512
    half8 a0[4], a1[4];
#pragma unroll
    for (int tn = 0; tn < 4; ++tn) {
      a0[tn] = *(const half8*)(wb + tn * 512);
      a1[tn] = *(const half8*)(wb + 2048 + tn * 512);
    }
#pragma unroll
    for (int tn = 0; tn < 4; ++tn) {
      float4_t bz = *(const float4_t*)(b0 + 64 * w + tn * 16 + q * 4);
#pragma unroll
      for (int tm = 0; tm < 4; ++tm) acc[tn][tm] = bz;
    }
#pragma unroll
    for (int kb = 0; kb < 2; ++kb) {
      half8 b[4];
#pragma unroll
      for (int tm = 0; tm < 4; ++tm) b[tm] = *(const half8*)(ap + tm * 16 * AST + kb * 32);
#pragma unroll
      for (int tn = 0; tn < 4; ++tn)
#pragma unroll
        for (int tm = 0; tm < 4; ++tm)
          acc[tn][tm] = __builtin_amdgcn_mfma_f32_16x16x32_f16(
              kb ? a1[tn] : a0[tn], b[tm], acc[tn][tm], 0, 0, 0);
    }
  }
  __syncthreads();                                   // (2) all E reads done
#pragma unroll
  for (int tn = 0; tn < 4; ++tn)
#pragma unroll
    for (int tm = 0; tm < 4; ++tm) {
      float4_t v = acc[tn][tm];
      *(half4_t*)&actX[(tm * 16 + c) * AST + 64 * w + tn * 16 + q * 4] =
          pack4(v[0], v[1], v[2], v[3]);
    }
  __syncthreads();                                   // (3) h ready

  // ---- layer 1 (+ part head): masked kb pair FIRST, snapshot after j==1 ----
  {
    const _Float16* wb = W1sw + (size_t)w * 16384 + l * 8;  // slice stride 8*4*512
    const int w2 = 2 * w;
    float bcw = bc[w];
#pragma unroll
    for (int tn = 0; tn < 4; ++tn) {
      float4_t bz = *(const float4_t*)(b1 + 64 * w + tn * 16 + q * 4);
#pragma unroll
      for (int tm = 0; tm < 4; ++tm) acc[tn][tm] = bz;
    }
    auto kbof = [&](int j) {
      return (j < 2) ? (w2 + j) : ((j - 2) + ((j - 2) >= w2 ? 2 : 0));
    };
    half8 A[2][4];
#pragma unroll
    for (int p = 0; p < 2; ++p) {
      const _Float16* pa = wb + kbof(p) * 2048;
#pragma unroll
      for (int tn = 0; tn < 4; ++tn) A[p][tn] = *(const half8*)(pa + tn * 512);
    }
#pragma unroll
    for (int j = 0; j < 8; ++j) {
      const int kb = kbof(j);
      half8 b[4];
#pragma unroll
      for (int tm = 0; tm < 4; ++tm) b[tm] = *(const half8*)(ap + tm * 16 * AST + kb * 32);
      // buffer j&1 holds kbof(j) -- consume BEFORE the prefetch below
      // overwrites it (2-buffer rotation, lookahead 2).
#pragma unroll
      for (int tn = 0; tn < 4; ++tn)
#pragma unroll
        for (int tm = 0; tm < 4; ++tm)
          acc[tn][tm] = __builtin_amdgcn_mfma_f32_16x16x32_f16(
              A[j & 1][tn], b[tm], acc[tn][tm], 0, 0, 0);
      if (j == 1) {
        // snapshot: acc = b1 + (x*mask_w) @ W1-slice -> class head for part w
        float pcls[4] = {0.f, 0.f, 0.f, 0.f};
#pragma unroll
        for (int tn = 0; tn < 4; ++tn) {
          float4_t wcv = *(const float4_t*)(Wc + 256 * w + 64 * w + tn * 16 + q * 4);
#pragma unroll
          for (int tm = 0; tm < 4; ++tm) {
            float4_t v = acc[tn][tm];
#pragma unroll
            for (int r = 0; r < 4; ++r) pcls[tm] += fmaxf(v[r], 0.f) * wcv[r];
          }
        }
#pragma unroll
        for (int tm = 0; tm < 4; ++tm) {
          float s = pcls[tm];
          s += __shfl_xor(s, 16, 64);
          s += __shfl_xor(s, 32, 64);
          if (l < 16)
            out[(size_t)NPTS + (size_t)(m0 + tm * 16 + c) * 4 + w] = s + bcw;
        }
      }
      if (j + 2 < 8) {   // prefetch AFTER use
        const _Float16* pa = wb + kbof(j + 2) * 2048;
#pragma unroll
        for (int tn = 0; tn < 4; ++tn) A[j & 1][tn] = *(const half8*)(pa + tn * 512);
      }
    }
  }
  __syncthreads();                                   // (4) all h reads done
#pragma unroll
  for (int tn = 0; tn < 4; ++tn)
#pragma unroll
    for (int tm = 0; tm < 4; ++tm) {
      float4_t v = acc[tn][tm];
      *(half4_t*)&actX[(tm * 16 + c) * AST + 64 * w + tn * 16 + q * 4] =
          pack4(fmaxf(v[0], 0.f), fmaxf(v[1], 0.f), fmaxf(v[2], 0.f), fmaxf(v[3], 0.f));
    }
  __syncthreads();                                   // (5) t1 ready

  // ---- layer 2 + occ head ----
  {
    const _Float16* wb = W2sw + (size_t)w * 16384 + l * 8;
#pragma unroll
    for (int tn = 0; tn < 4; ++tn) {
      float4_t bz = *(const float4_t*)(b2 + 64 * w + tn * 16 + q * 4);
#pragma unroll
      for (int tm = 0; tm < 4; ++tm) acc[tn][tm] = bz;
    }
    half8 A[2][4];
#pragma unroll
    for (int p = 0; p < 2; ++p)
#pragma unroll
      for (int tn = 0; tn < 4; ++tn)
        A[p][tn] = *(const half8*)(wb + p * 2048 + tn * 512);
#pragma unroll
    for (int kb = 0; kb < 8; ++kb) {
      half8 b[4];
#pragma unroll
      for (int tm = 0; tm < 4; ++tm) b[tm] = *(const half8*)(ap + tm * 16 * AST + kb * 32);
#pragma unroll
      for (int tn = 0; tn < 4; ++tn)
#pragma unroll
        for (int tm = 0; tm < 4; ++tm)
          acc[tn][tm] = __builtin_amdgcn_mfma_f32_16x16x32_f16(
              A[kb & 1][tn], b[tm], acc[tn][tm], 0, 0, 0);
      if (kb + 2 < 8) {
#pragma unroll
        for (int tn = 0; tn < 4; ++tn)
          A[kb & 1][tn] = *(const half8*)(wb + (kb + 2) * 2048 + tn * 512);
      }
    }
    float pocc[4] = {0.f, 0.f, 0.f, 0.f};
#pragma unroll
    for (int tn = 0; tn < 4; ++tn) {
      float4_t wov = *(const float4_t*)(Wocc + 64 * w + tn * 16 + q * 4);
#pragma unroll
      for (int tm = 0; tm < 4; ++tm) {
        float4_t v = acc[tn][tm];
#pragma unroll
        for (int r = 0; r < 4; ++r) pocc[tm] += fmaxf(v[r], 0.f) * wov[r];
      }
    }
#pragma unroll
    for (int tm = 0; tm < 4; ++tm) {
      float s = pocc[tm];
      s += __shfl_xor(s, 16, 64);
      s += __shfl_xor(s, 32, 64);
      if (l < 16) occ_s[w][tm * 16 + c] = s;
    }
  }
  __syncthreads();                                   // (6) occ partials ready
  if (t < M_PB) {
    out[m0 + t] = occ_s[0][t] + occ_s[1][t] + occ_s[2][t] + occ_s[3][t] + bocc[0];
  }
}

extern "C" void kernel_launch(void* const* d_in, const int* in_sizes, int n_in,
                              void* d_out, int out_size, void* d_ws, size_t ws_size,
                              hipStream_t stream) {
  const float* coords = (const float*)d_in[0];
  const float* W0   = (const float*)d_in[1];
  const float* b0   = (const float*)d_in[2];
  const float* W1   = (const float*)d_in[3];
  const float* b1   = (const float*)d_in[4];
  const float* W2   = (const float*)d_in[5];
  const float* b2   = (const float*)d_in[6];
  const float* Wocc = (const float*)d_in[7];
  const float* bocc = (const float*)d_in[8];
  const float* Wc   = (const float*)d_in[9];
  const float* bc   = (const float*)d_in[10];
  float* out = (float*)d_out;

  _Float16* ws = (_Float16*)d_ws;       // W0sw[16384] | W1sw[65536] | W2sw[65536]
  _Float16* W0sw = ws;
  _Float16* W1sw = ws + 16384;
  _Float16* W2sw = ws + 81920;

  prep<<<576, 256, 0, stream>>>(W0, W1, W2, ws);
  mlp_main<<<NPTS / M_PB, 256, 0, stream>>>(coords, W0sw, W1sw, W2sw,
                                            b0, b1, b2, Wocc, bocc, Wc, bc, out);
}

// Round 2
// 115.633 us; speedup vs baseline: 1.0522x; 1.0522x over previous
//
#include <hip/hip_runtime.h>

// MLP3D fused, MI355X gfx950 — round 9: fix r8's spill.
// r8 (M_PB=64, __launch_bounds__(256,4)) regressed 48.6->60us: the 4-blocks/CU
// bound capped waves at 128 total regs; allocator gave 64 arch + 64 AGPR and
// spilled A-buffers/b-frags to scratch (WRITE_SIZE 5.1->52.9MB = spill traffic).
// r9: identical structure, __launch_bounds__(256,3) -> ~168-reg budget,
// spill-free at ~160 live, 3 blocks/CU = 12 waves/CU (vs r7's 8).
// Prefetch discipline unchanged: A[j&1] reloaded only AFTER its MFMA consumer.

#define NPTS 131072
#define M_PB 64
#define AST 264   // activation row stride in halves (256+8)

typedef _Float16 half8   __attribute__((ext_vector_type(8)));
typedef _Float16 half4_t __attribute__((ext_vector_type(4)));
typedef __fp16   fp16x2  __attribute__((ext_vector_type(2)));
typedef float    float4_t __attribute__((ext_vector_type(4)));

// ---- prep: W (f32 [K][256]) -> f16 per-wave-contiguous fragment layout ----
// dst[(((s*KB + kb)*4 + tn)*64 + l)*8 + j] = W[(kb*32 + (l>>4)*8 + j)*256 + s*64 + tn*16 + (l&15)]
__global__ void prep(const float* __restrict__ W0, const float* __restrict__ W1,
                     const float* __restrict__ W2, _Float16* __restrict__ ws) {
  int id = blockIdx.x * 256 + threadIdx.x;   // 147456 total
  _Float16 v;
  if (id < 16384) {            // W0sw: 4 slices x 2 kb x 4 tn x 512
    int e = id, j = e & 7, l = (e >> 3) & 63, tn = (e >> 9) & 3, kb = (e >> 11) & 1, s = e >> 12;
    int k = kb * 32 + (l >> 4) * 8 + j, n = s * 64 + tn * 16 + (l & 15);
    v = (k < 63) ? (_Float16)W0[k * 256 + n] : (_Float16)0.f;
  } else if (id < 81920) {     // W1sw: 4 x 8 x 4 x 512
    int e = id - 16384, j = e & 7, l = (e >> 3) & 63, tn = (e >> 9) & 3, kb = (e >> 11) & 7, s = e >> 14;
    int k = kb * 32 + (l >> 4) * 8 + j, n = s * 64 + tn * 16 + (l & 15);
    v = (_Float16)W1[k * 256 + n];
  } else {                     // W2sw
    int e = id - 81920, j = e & 7, l = (e >> 3) & 63, tn = (e >> 9) & 3, kb = (e >> 11) & 7, s = e >> 14;
    int k = kb * 32 + (l >> 4) * 8 + j, n = s * 64 + tn * 16 + (l & 15);
    v = (_Float16)W2[k * 256 + n];
  }
  ws[id] = v;
}

__device__ __forceinline__ half4_t pack4(float a, float b, float cc, float d) {
  fp16x2 p0 = __builtin_amdgcn_cvt_pkrtz(a, b);
  fp16x2 p1 = __builtin_amdgcn_cvt_pkrtz(cc, d);
  half4_t h;
  h[0] = (_Float16)p0[0]; h[1] = (_Float16)p0[1];
  h[2] = (_Float16)p1[0]; h[3] = (_Float16)p1[1];
  return h;
}

__global__ __launch_bounds__(256, 3) void mlp_main(
    const float* __restrict__ coords,
    const _Float16* __restrict__ W0sw,
    const _Float16* __restrict__ W1sw,
    const _Float16* __restrict__ W2sw,
    const float* __restrict__ b0, const float* __restrict__ b1,
    const float* __restrict__ b2,
    const float* __restrict__ Wocc, const float* __restrict__ bocc,
    const float* __restrict__ Wc, const float* __restrict__ bc,
    float* __restrict__ out) {
  __shared__ _Float16 actX[M_PB * AST];   // E -> h -> t1 (one buffer, barriered)
  __shared__ float occ_s[4][M_PB];

  const int t = threadIdx.x;
  const int w = t >> 6;          // wave = neuron slice [64w,64w+64) = part id
  const int l = t & 63;
  const int c = l & 15;
  const int q = l >> 4;
  const int m0 = blockIdx.x * M_PB;

  // ---- positional encoding: 4 threads/point, 16 k-values each ----
  {
    int m = t & 63, kh = (t >> 6) * 16;   // kh wave-uniform
    const float* cp = coords + (size_t)(m0 + m) * 3;
    float x0 = cp[0], x1 = cp[1], x2 = cp[2];
#pragma unroll
    for (int i = 0; i < 2; ++i) {
      float v[8];
#pragma unroll
      for (int u = 0; u < 8; ++u) {
        int k = kh + i * 8 + u;
        float r;
        if (k >= 63) r = 0.f;
        else if (k < 3) r = (k == 0) ? x0 : (k == 1 ? x1 : x2);
        else {
          int kk = k - 3;
          int f = kk / 6;
          int rem = kk - 6 * f;
          int s = (rem >= 3) ? 1 : 0;
          int i3 = rem - 3 * s;
          float xi = (i3 == 0) ? x0 : (i3 == 1 ? x1 : x2);
          float arg = xi * (float)(1 << f);
          float nn = rintf(arg * 0.15915494309189535f);
          float rr = fmaf(nn, -6.28318548202514648f, arg);
          rr = fmaf(nn, 1.7484555e-7f, rr);
          r = s ? __cosf(rr) : __sinf(rr);
        }
        v[u] = r;
      }
      half8 ev;
#pragma unroll
      for (int u = 0; u < 4; ++u) {
        fp16x2 p = __builtin_amdgcn_cvt_pkrtz(v[2 * u], v[2 * u + 1]);
        ev[2 * u] = (_Float16)p[0]; ev[2 * u + 1] = (_Float16)p[1];
      }
      *(half8*)&actX[m * AST + kh + i * 8] = ev;
    }
  }
  __syncthreads();                                   // (1) E ready

  float4_t acc[4][4];
  const _Float16* ap = actX + c * AST + q * 8;

  // ---- layer 0: h = E @ W0 + b0 (no relu), K=64 (2 kb, all A upfront) ----
  {
    const _Float16* wb = W0sw + (size_t)w * 4096 + l * 8;  // slice stride 2*4*512
    half8 a0[4], a1[4];
#pragma unroll
    for (int tn = 0; tn < 4; ++tn) {
      a0[tn] = *(const half8*)(wb + tn * 512);
      a1[tn] = *(const half8*)(wb + 2048 + tn * 512);
    }
#pragma unroll
    for (int tn = 0; tn < 4; ++tn) {
      float4_t bz = *(const float4_t*)(b0 + 64 * w + tn * 16 + q * 4);
#pragma unroll
      for (int tm = 0; tm < 4; ++tm) acc[tn][tm] = bz;
    }
#pragma unroll
    for (int kb = 0; kb < 2; ++kb) {
      half8 b[4];
#pragma unroll
      for (int tm = 0; tm < 4; ++tm) b[tm] = *(const half8*)(ap + tm * 16 * AST + kb * 32);
#pragma unroll
      for (int tn = 0; tn < 4; ++tn)
#pragma unroll
        for (int tm = 0; tm < 4; ++tm)
          acc[tn][tm] = __builtin_amdgcn_mfma_f32_16x16x32_f16(
              kb ? a1[tn] : a0[tn], b[tm], acc[tn][tm], 0, 0, 0);
    }
  }
  __syncthreads();                                   // (2) all E reads done
#pragma unroll
  for (int tn = 0; tn < 4; ++tn)
#pragma unroll
    for (int tm = 0; tm < 4; ++tm) {
      float4_t v = acc[tn][tm];
      *(half4_t*)&actX[(tm * 16 + c) * AST + 64 * w + tn * 16 + q * 4] =
          pack4(v[0], v[1], v[2], v[3]);
    }
  __syncthreads();                                   // (3) h ready

  // ---- layer 1 (+ part head): masked kb pair FIRST, snapshot after j==1 ----
  {
    const _Float16* wb = W1sw + (size_t)w * 16384 + l * 8;  // slice stride 8*4*512
    const int w2 = 2 * w;
    float bcw = bc[w];
#pragma unroll
    for (int tn = 0; tn < 4; ++tn) {
      float4_t bz = *(const float4_t*)(b1 + 64 * w + tn * 16 + q * 4);
#pragma unroll
      for (int tm = 0; tm < 4; ++tm) acc[tn][tm] = bz;
    }
    auto kbof = [&](int j) {
      return (j < 2) ? (w2 + j) : ((j - 2) + ((j - 2) >= w2 ? 2 : 0));
    };
    half8 A[2][4];
#pragma unroll
    for (int p = 0; p < 2; ++p) {
      const _Float16* pa = wb + kbof(p) * 2048;
#pragma unroll
      for (int tn = 0; tn < 4; ++tn) A[p][tn] = *(const half8*)(pa + tn * 512);
    }
#pragma unroll
    for (int j = 0; j < 8; ++j) {
      const int kb = kbof(j);
      half8 b[4];
#pragma unroll
      for (int tm = 0; tm < 4; ++tm) b[tm] = *(const half8*)(ap + tm * 16 * AST + kb * 32);
      // buffer j&1 holds kbof(j) -- consume BEFORE the prefetch below
      // overwrites it (2-buffer rotation, lookahead 2).
#pragma unroll
      for (int tn = 0; tn < 4; ++tn)
#pragma unroll
        for (int tm = 0; tm < 4; ++tm)
          acc[tn][tm] = __builtin_amdgcn_mfma_f32_16x16x32_f16(
              A[j & 1][tn], b[tm], acc[tn][tm], 0, 0, 0);
      if (j == 1) {
        // snapshot: acc = b1 + (x*mask_w) @ W1-slice -> class head for part w
        float pcls[4] = {0.f, 0.f, 0.f, 0.f};
#pragma unroll
        for (int tn = 0; tn < 4; ++tn) {
          float4_t wcv = *(const float4_t*)(Wc + 256 * w + 64 * w + tn * 16 + q * 4);
#pragma unroll
          for (int tm = 0; tm < 4; ++tm) {
            float4_t v = acc[tn][tm];
#pragma unroll
            for (int r = 0; r < 4; ++r) pcls[tm] += fmaxf(v[r], 0.f) * wcv[r];
          }
        }
#pragma unroll
        for (int tm = 0; tm < 4; ++tm) {
          float s = pcls[tm];
          s += __shfl_xor(s, 16, 64);
          s += __shfl_xor(s, 32, 64);
          if (l < 16)
            out[(size_t)NPTS + (size_t)(m0 + tm * 16 + c) * 4 + w] = s + bcw;
        }
      }
      if (j + 2 < 8) {   // prefetch AFTER use
        const _Float16* pa = wb + kbof(j + 2) * 2048;
#pragma unroll
        for (int tn = 0; tn < 4; ++tn) A[j & 1][tn] = *(const half8*)(pa + tn * 512);
      }
    }
  }
  __syncthreads();                                   // (4) all h reads done
#pragma unroll
  for (int tn = 0; tn < 4; ++tn)
#pragma unroll
    for (int tm = 0; tm < 4; ++tm) {
      float4_t v = acc[tn][tm];
      *(half4_t*)&actX[(tm * 16 + c) * AST + 64 * w + tn * 16 + q * 4] =
          pack4(fmaxf(v[0], 0.f), fmaxf(v[1], 0.f), fmaxf(v[2], 0.f), fmaxf(v[3], 0.f));
    }
  __syncthreads();                                   // (5) t1 ready

  // ---- layer 2 + occ head ----
  {
    const _Float16* wb = W2sw + (size_t)w * 16384 + l * 8;
#pragma unroll
    for (int tn = 0; tn < 4; ++tn) {
      float4_t bz = *(const float4_t*)(b2 + 64 * w + tn * 16 + q * 4);
#pragma unroll
      for (int tm = 0; tm < 4; ++tm) acc[tn][tm] = bz;
    }
    half8 A[2][4];
#pragma unroll
    for (int p = 0; p < 2; ++p)
#pragma unroll
      for (int tn = 0; tn < 4; ++tn)
        A[p][tn] = *(const half8*)(wb + p * 2048 + tn * 512);
#pragma unroll
    for (int kb = 0; kb < 8; ++kb) {
      half8 b[4];
#pragma unroll
      for (int tm = 0; tm < 4; ++tm) b[tm] = *(const half8*)(ap + tm * 16 * AST + kb * 32);
#pragma unroll
      for (int tn = 0; tn < 4; ++tn)
#pragma unroll
        for (int tm = 0; tm < 4; ++tm)
          acc[tn][tm] = __builtin_amdgcn_mfma_f32_16x16x32_f16(
              A[kb & 1][tn], b[tm], acc[tn][tm], 0, 0, 0);
      if (kb + 2 < 8) {
#pragma unroll
        for (int tn = 0; tn < 4; ++tn)
          A[kb & 1][tn] = *(const half8*)(wb + (kb + 2) * 2048 + tn * 512);
      }
    }
    float pocc[4] = {0.f, 0.f, 0.f, 0.f};
#pragma unroll
    for (int tn = 0; tn < 4; ++tn) {
      float4_t wov = *(const float4_t*)(Wocc + 64 * w + tn * 16 + q * 4);
#pragma unroll
      for (int tm = 0; tm < 4; ++tm) {
        float4_t v = acc[tn][tm];
#pragma unroll
        for (int r = 0; r < 4; ++r) pocc[tm] += fmaxf(v[r], 0.f) * wov[r];
      }
    }
#pragma unroll
    for (int tm = 0; tm < 4; ++tm) {
      float s = pocc[tm];
      s += __shfl_xor(s, 16, 64);
      s += __shfl_xor(s, 32, 64);
      if (l < 16) occ_s[w][tm * 16 + c] = s;
    }
  }
  __syncthreads();                                   // (6) occ partials ready
  if (t < M_PB) {
    out[m0 + t] = occ_s[0][t] + occ_s[1][t] + occ_s[2][t] + occ_s[3][t] + bocc[0];
  }
}

extern "C" void kernel_launch(void* const* d_in, const int* in_sizes, int n_in,
                              void* d_out, int out_size, void* d_ws, size_t ws_size,
                              hipStream_t stream) {
  const float* coords = (const float*)d_in[0];
  const float* W0   = (const float*)d_in[1];
  const float* b0   = (const float*)d_in[2];
  const float* W1   = (const float*)d_in[3];
  const float* b1   = (const float*)d_in[4];
  const float* W2   = (const float*)d_in[5];
  const float* b2   = (const float*)d_in[6];
  const float* Wocc = (const float*)d_in[7];
  const float* bocc = (const float*)d_in[8];
  const float* Wc   = (const float*)d_in[9];
  const float* bc   = (const float*)d_in[10];
  float* out = (float*)d_out;

  _Float16* ws = (_Float16*)d_ws;       // W0sw[16384] | W1sw[65536] | W2sw[65536]
  _Float16* W0sw = ws;
  _Float16* W1sw = ws + 16384;
  _Float16* W2sw = ws + 81920;

  prep<<<576, 256, 0, stream>>>(W0, W1, W2, ws);
  mlp_main<<<NPTS / M_PB, 256, 0, stream>>>(coords, W0sw, W1sw, W2sw,
                                            b0, b1, b2, Wocc, bocc, Wc, bc, out);
}

// Round 3
// 114.924 us; speedup vs baseline: 1.0587x; 1.0062x over previous
//
#include <hip/hip_runtime.h>

// MLP3D fused, MI355X gfx950 — round 10: r7 revert + LDS bank-conflict fix.
// r9 confirmed M_PB=64 loses (2x weight L2 traffic, half tm reuse): 56.2 vs 48.6us.
// r10 = r7 structure (M_PB=128, acc[4][8], 3-buffer A-prefetch, lb(256,2))
// with AST 264 -> 268. Rationale: AST=264 gives row stride 132 dwords = 4 mod 32,
// so every 16B B-read window lands on one of only 8 bank-groups (8-way alias;
// SQ_LDS_BANK_CONFLICT constant 3.4M across r7/r8/r9). AST=268 -> 134 dwords =
// 6 mod 32: 16 distinct window starts per quarter-wave, ~2-way (free).
// Rows are now 8B-aligned only, so all 16B LDS accesses are split into half4
// pairs (ds_read2_b64-class); stores were already 8B.
// Register discipline: r7 sits exactly at the 256-reg/wave cliff (128 arch +
// 128 AGPR) — no hoisting, no extra live state vs r7.

#define NPTS 131072
#define M_PB 128
#define AST 268   // activation row stride in halves (256+12): 6 dwords mod 32

typedef _Float16 half8   __attribute__((ext_vector_type(8)));
typedef _Float16 half4_t __attribute__((ext_vector_type(4)));
typedef __fp16   fp16x2  __attribute__((ext_vector_type(2)));
typedef float    float4_t __attribute__((ext_vector_type(4)));

// ---- prep: W (f32 [K][256]) -> f16 per-wave-contiguous fragment layout ----
// dst[(((s*KB + kb)*4 + tn)*64 + l)*8 + j] = W[(kb*32 + (l>>4)*8 + j)*256 + s*64 + tn*16 + (l&15)]
__global__ void prep(const float* __restrict__ W0, const float* __restrict__ W1,
                     const float* __restrict__ W2, _Float16* __restrict__ ws) {
  int id = blockIdx.x * 256 + threadIdx.x;   // 147456 total
  _Float16 v;
  if (id < 16384) {            // W0sw: 4 slices x 2 kb x 4 tn x 512
    int e = id, j = e & 7, l = (e >> 3) & 63, tn = (e >> 9) & 3, kb = (e >> 11) & 1, s = e >> 12;
    int k = kb * 32 + (l >> 4) * 8 + j, n = s * 64 + tn * 16 + (l & 15);
    v = (k < 63) ? (_Float16)W0[k * 256 + n] : (_Float16)0.f;
  } else if (id < 81920) {     // W1sw: 4 x 8 x 4 x 512
    int e = id - 16384, j = e & 7, l = (e >> 3) & 63, tn = (e >> 9) & 3, kb = (e >> 11) & 7, s = e >> 14;
    int k = kb * 32 + (l >> 4) * 8 + j, n = s * 64 + tn * 16 + (l & 15);
    v = (_Float16)W1[k * 256 + n];
  } else {                     // W2sw
    int e = id - 81920, j = e & 7, l = (e >> 3) & 63, tn = (e >> 9) & 3, kb = (e >> 11) & 7, s = e >> 14;
    int k = kb * 32 + (l >> 4) * 8 + j, n = s * 64 + tn * 16 + (l & 15);
    v = (_Float16)W2[k * 256 + n];
  }
  ws[id] = v;
}

__device__ __forceinline__ half4_t pack4(float a, float b, float cc, float d) {
  fp16x2 p0 = __builtin_amdgcn_cvt_pkrtz(a, b);
  fp16x2 p1 = __builtin_amdgcn_cvt_pkrtz(cc, d);
  half4_t h;
  h[0] = (_Float16)p0[0]; h[1] = (_Float16)p0[1];
  h[2] = (_Float16)p1[0]; h[3] = (_Float16)p1[1];
  return h;
}

// 16B logical load as two 8B LDS loads (rows are 8B-aligned with AST=268)
__device__ __forceinline__ half8 ld8(const _Float16* p) {
  half4_t lo = *(const half4_t*)p;
  half4_t hi = *(const half4_t*)(p + 4);
  half8 r;
  r[0] = lo[0]; r[1] = lo[1]; r[2] = lo[2]; r[3] = lo[3];
  r[4] = hi[0]; r[5] = hi[1]; r[6] = hi[2]; r[7] = hi[3];
  return r;
}

__global__ __launch_bounds__(256, 2) void mlp_main(
    const float* __restrict__ coords,
    const _Float16* __restrict__ W0sw,
    const _Float16* __restrict__ W1sw,
    const _Float16* __restrict__ W2sw,
    const float* __restrict__ b0, const float* __restrict__ b1,
    const float* __restrict__ b2,
    const float* __restrict__ Wocc, const float* __restrict__ bocc,
    const float* __restrict__ Wc, const float* __restrict__ bc,
    float* __restrict__ out) {
  __shared__ _Float16 actX[M_PB * AST];   // E -> h -> t1 (one buffer, barriered)
  __shared__ float occ_s[4][M_PB];

  const int t = threadIdx.x;
  const int w = t >> 6;          // wave = neuron slice [64w,64w+64) = part id
  const int l = t & 63;
  const int c = l & 15;
  const int q = l >> 4;
  const int m0 = blockIdx.x * M_PB;

  // ---- positional encoding: 2 threads/point, 32 k-values each ----
  {
    int m = t & 127, kh = (t >> 7) * 32;   // kh wave-uniform
    const float* cp = coords + (size_t)(m0 + m) * 3;
    float x0 = cp[0], x1 = cp[1], x2 = cp[2];
#pragma unroll
    for (int i = 0; i < 4; ++i) {
      float v[8];
#pragma unroll
      for (int u = 0; u < 8; ++u) {
        int k = kh + i * 8 + u;
        float r;
        if (k >= 63) r = 0.f;
        else if (k < 3) r = (k == 0) ? x0 : (k == 1 ? x1 : x2);
        else {
          int kk = k - 3;
          int f = kk / 6;
          int rem = kk - 6 * f;
          int s = (rem >= 3) ? 1 : 0;
          int i3 = rem - 3 * s;
          float xi = (i3 == 0) ? x0 : (i3 == 1 ? x1 : x2);
          float arg = xi * (float)(1 << f);
          float nn = rintf(arg * 0.15915494309189535f);
          float rr = fmaf(nn, -6.28318548202514648f, arg);
          rr = fmaf(nn, 1.7484555e-7f, rr);
          r = s ? __cosf(rr) : __sinf(rr);
        }
        v[u] = r;
      }
      // two 8B stores (row base only 8B-aligned with AST=268)
      half4_t e0 = pack4(v[0], v[1], v[2], v[3]);
      half4_t e1 = pack4(v[4], v[5], v[6], v[7]);
      *(half4_t*)&actX[m * AST + kh + i * 8] = e0;
      *(half4_t*)&actX[m * AST + kh + i * 8 + 4] = e1;
    }
  }
  __syncthreads();                                   // (1) E ready

  float4_t acc[4][8];
  const _Float16* ap = actX + c * AST + q * 8;

  // ---- layer 0: h = E @ W0 + b0 (no relu), K=64 (2 kb, all A upfront) ----
  {
    const _Float16* wb = W0sw + (size_t)w * 4096 + l * 8;  // slice stride 2*4*512
    half8 a0[4], a1[4];
#pragma unroll
    for (int tn = 0; tn < 4; ++tn) {
      a0[tn] = *(const half8*)(wb + tn * 512);
      a1[tn] = *(const half8*)(wb + 2048 + tn * 512);
    }
#pragma unroll
    for (int tn = 0; tn < 4; ++tn) {
      float4_t bz = *(const float4_t*)(b0 + 64 * w + tn * 16 + q * 4);
#pragma unroll
      for (int tm = 0; tm < 8; ++tm) acc[tn][tm] = bz;
    }
#pragma unroll
    for (int kb = 0; kb < 2; ++kb) {
      half8 b[8];
#pragma unroll
      for (int tm = 0; tm < 8; ++tm) b[tm] = ld8(ap + tm * 16 * AST + kb * 32);
#pragma unroll
      for (int tn = 0; tn < 4; ++tn)
#pragma unroll
        for (int tm = 0; tm < 8; ++tm)
          acc[tn][tm] = __builtin_amdgcn_mfma_f32_16x16x32_f16(
              kb ? a1[tn] : a0[tn], b[tm], acc[tn][tm], 0, 0, 0);
    }
  }
  __syncthreads();                                   // (2) all E reads done
#pragma unroll
  for (int tn = 0; tn < 4; ++tn)
#pragma unroll
    for (int tm = 0; tm < 8; ++tm) {
      float4_t v = acc[tn][tm];
      *(half4_t*)&actX[(tm * 16 + c) * AST + 64 * w + tn * 16 + q * 4] =
          pack4(v[0], v[1], v[2], v[3]);
    }
  __syncthreads();                                   // (3) h ready

  // ---- layer 1 (+ part head): masked kb pair FIRST, snapshot after j==1 ----
  {
    const _Float16* wb = W1sw + (size_t)w * 16384 + l * 8;  // slice stride 8*4*512
    const int w2 = 2 * w;
    float bcw = bc[w];
#pragma unroll
    for (int tn = 0; tn < 4; ++tn) {
      float4_t bz = *(const float4_t*)(b1 + 64 * w + tn * 16 + q * 4);
#pragma unroll
      for (int tm = 0; tm < 8; ++tm) acc[tn][tm] = bz;
    }
    auto kbof = [&](int j) {
      return (j < 2) ? (w2 + j) : ((j - 2) + ((j - 2) >= w2 ? 2 : 0));
    };
    half8 A[3][4];
#pragma unroll
    for (int p = 0; p < 3; ++p) {
      const _Float16* pa = wb + kbof(p) * 2048;
#pragma unroll
      for (int tn = 0; tn < 4; ++tn) A[p][tn] = *(const half8*)(pa + tn * 512);
    }
#pragma unroll
    for (int j = 0; j < 8; ++j) {
      const int kb = kbof(j);
      half8 b[8];
#pragma unroll
      for (int tm = 0; tm < 8; ++tm) b[tm] = ld8(ap + tm * 16 * AST + kb * 32);
      // use buffer j%3 (holds kbof(j)) -- MUST consume before the prefetch
      // below overwrites the same buffer (3-buffer rotation, lookahead 3).
#pragma unroll
      for (int tn = 0; tn < 4; ++tn)
#pragma unroll
        for (int tm = 0; tm < 8; ++tm)
          acc[tn][tm] = __builtin_amdgcn_mfma_f32_16x16x32_f16(
              A[j % 3][tn], b[tm], acc[tn][tm], 0, 0, 0);
      if (j == 1) {
        // snapshot: acc = b1 + (x*mask_w) @ W1-slice -> class head for part w
        float pcls[8] = {0.f, 0.f, 0.f, 0.f, 0.f, 0.f, 0.f, 0.f};
#pragma unroll
        for (int tn = 0; tn < 4; ++tn) {
          float4_t wcv = *(const float4_t*)(Wc + 256 * w + 64 * w + tn * 16 + q * 4);
#pragma unroll
          for (int tm = 0; tm < 8; ++tm) {
            float4_t v = acc[tn][tm];
#pragma unroll
            for (int r = 0; r < 4; ++r) pcls[tm] += fmaxf(v[r], 0.f) * wcv[r];
          }
        }
#pragma unroll
        for (int tm = 0; tm < 8; ++tm) {
          float s = pcls[tm];
          s += __shfl_xor(s, 16, 64);
          s += __shfl_xor(s, 32, 64);
          if (l < 16)
            out[(size_t)NPTS + (size_t)(m0 + tm * 16 + c) * 4 + w] = s + bcw;
        }
      }
      if (j + 3 < 8) {   // prefetch AFTER use
        const _Float16* pa = wb + kbof(j + 3) * 2048;
#pragma unroll
        for (int tn = 0; tn < 4; ++tn) A[j % 3][tn] = *(const half8*)(pa + tn * 512);
      }
    }
  }
  __syncthreads();                                   // (4) all h reads done
#pragma unroll
  for (int tn = 0; tn < 4; ++tn)
#pragma unroll
    for (int tm = 0; tm < 8; ++tm) {
      float4_t v = acc[tn][tm];
      *(half4_t*)&actX[(tm * 16 + c) * AST + 64 * w + tn * 16 + q * 4] =
          pack4(fmaxf(v[0], 0.f), fmaxf(v[1], 0.f), fmaxf(v[2], 0.f), fmaxf(v[3], 0.f));
    }
  __syncthreads();                                   // (5) t1 ready

  // ---- layer 2 + occ head ----
  {
    const _Float16* wb = W2sw + (size_t)w * 16384 + l * 8;
#pragma unroll
    for (int tn = 0; tn < 4; ++tn) {
      float4_t bz = *(const float4_t*)(b2 + 64 * w + tn * 16 + q * 4);
#pragma unroll
      for (int tm = 0; tm < 8; ++tm) acc[tn][tm] = bz;
    }
    half8 A[3][4];
#pragma unroll
    for (int p = 0; p < 3; ++p)
#pragma unroll
      for (int tn = 0; tn < 4; ++tn)
        A[p][tn] = *(const half8*)(wb + p * 2048 + tn * 512);
#pragma unroll
    for (int kb = 0; kb < 8; ++kb) {
      half8 b[8];
#pragma unroll
      for (int tm = 0; tm < 8; ++tm) b[tm] = ld8(ap + tm * 16 * AST + kb * 32);
#pragma unroll
      for (int tn = 0; tn < 4; ++tn)
#pragma unroll
        for (int tm = 0; tm < 8; ++tm)
          acc[tn][tm] = __builtin_amdgcn_mfma_f32_16x16x32_f16(
              A[kb % 3][tn], b[tm], acc[tn][tm], 0, 0, 0);
      if (kb + 3 < 8) {
#pragma unroll
        for (int tn = 0; tn < 4; ++tn)
          A[kb % 3][tn] = *(const half8*)(wb + (kb + 3) * 2048 + tn * 512);
      }
    }
    float pocc[8] = {0.f, 0.f, 0.f, 0.f, 0.f, 0.f, 0.f, 0.f};
#pragma unroll
    for (int tn = 0; tn < 4; ++tn) {
      float4_t wov = *(const float4_t*)(Wocc + 64 * w + tn * 16 + q * 4);
#pragma unroll
      for (int tm = 0; tm < 8; ++tm) {
        float4_t v = acc[tn][tm];
#pragma unroll
        for (int r = 0; r < 4; ++r) pocc[tm] += fmaxf(v[r], 0.f) * wov[r];
      }
    }
#pragma unroll
    for (int tm = 0; tm < 8; ++tm) {
      float s = pocc[tm];
      s += __shfl_xor(s, 16, 64);
      s += __shfl_xor(s, 32, 64);
      if (l < 16) occ_s[w][tm * 16 + c] = s;
    }
  }
  __syncthreads();                                   // (6) occ partials ready
  if (t < M_PB) {
    out[m0 + t] = occ_s[0][t] + occ_s[1][t] + occ_s[2][t] + occ_s[3][t] + bocc[0];
  }
}

extern "C" void kernel_launch(void* const* d_in, const int* in_sizes, int n_in,
                              void* d_out, int out_size, void* d_ws, size_t ws_size,
                              hipStream_t stream) {
  const float* coords = (const float*)d_in[0];
  const float* W0   = (const float*)d_in[1];
  const float* b0   = (const float*)d_in[2];
  const float* W1   = (const float*)d_in[3];
  const float* b1   = (const float*)d_in[4];
  const float* W2   = (const float*)d_in[5];
  const float* b2   = (const float*)d_in[6];
  const float* Wocc = (const float*)d_in[7];
  const float* bocc = (const float*)d_in[8];
  const float* Wc   = (const float*)d_in[9];
  const float* bc   = (const float*)d_in[10];
  float* out = (float*)d_out;

  _Float16* ws = (_Float16*)d_ws;       // W0sw[16384] | W1sw[65536] | W2sw[65536]
  _Float16* W0sw = ws;
  _Float16* W1sw = ws + 16384;
  _Float16* W2sw = ws + 81920;

  prep<<<576, 256, 0, stream>>>(W0, W1, W2, ws);
  mlp_main<<<NPTS / M_PB, 256, 0, stream>>>(coords, W0sw, W1sw, W2sw,
                                            b0, b1, b2, Wocc, bocc, Wc, bc, out);
}